// Round 13
// baseline (483.297 us; speedup 1.0000x reference)
//
#include <hip/hip_runtime.h>
#include <hip/hip_bf16.h>
#include <math.h>

#define N_NODES 40000
#define E_EDGES 60000
#define R_REL 6
#define IN_F 32
#define HID_F 128
#define B_GRAPHS 2000
#define NODES_PER_G 20
#define NEG_SLOPE 0.2f
#define NB (R_REL * N_NODES)            // 240000 bins
#define NTOT (R_REL * (E_EDGES + N_NODES))  // 600000 entries incl. self-loops
#define NBLK ((NB + 255) / 256)         // 938 scan blocks

typedef __bf16 bf16x8 __attribute__((ext_vector_type(8)));
typedef float f32x4 __attribute__((ext_vector_type(4)));

__device__ __forceinline__ unsigned f2bfbits(float f) {
    unsigned u = __builtin_bit_cast(unsigned, f);
    return (u + 0x7FFFu + ((u >> 16) & 1u)) >> 16;   // RNE
}
__device__ __forceinline__ float bflo(unsigned u) { return __builtin_bit_cast(float, u << 16); }
__device__ __forceinline__ float bfhi(unsigned u) { return __builtin_bit_cast(float, u & 0xFFFF0000u); }

// ---------------- CSR build: count (edges + self-loops) ----------------
__global__ __launch_bounds__(256) void count_kernel(
    const int* __restrict__ ei, int* __restrict__ cnt)
{
    int idx = blockIdx.x * 256 + threadIdx.x;
    if (idx >= NTOT) return;
    int bin;
    if (idx < R_REL * E_EDGES) {
        int r = idx / E_EDGES, e = idx - r * E_EDGES;
        bin = r * N_NODES + ei[(size_t)r * 2 * E_EDGES + E_EDGES + e];
    } else {
        bin = idx - R_REL * E_EDGES;   // self-loop: bin == r*N+d
    }
    atomicAdd(&cnt[bin], 1);
}

// ---------------- CSR build: scan level 1 (per-256 block) ----------------
__global__ __launch_bounds__(256) void scan1_kernel(
    const int* __restrict__ cnt, int* __restrict__ part, int* __restrict__ bsum)
{
    int i = blockIdx.x * 256 + threadIdx.x;
    int v = (i < NB) ? cnt[i] : 0;
    int lane = threadIdx.x & 63, w = threadIdx.x >> 6;
    int x = v;
#pragma unroll
    for (int off = 1; off < 64; off <<= 1) {
        int y = __shfl_up(x, off, 64);
        if (lane >= off) x += y;
    }
    __shared__ int ws[4];
    if (lane == 63) ws[w] = x;
    __syncthreads();
    int add = 0;
    for (int j = 0; j < w; j++) add += ws[j];
    int incl = x + add;
    if (i < NB) part[i] = incl - v;           // exclusive within block
    if (threadIdx.x == 255) bsum[blockIdx.x] = incl;
}

// ---------------- CSR build: scan level 2 (block sums, single block) ---------
__global__ __launch_bounds__(1024) void scan2_kernel(
    const int* __restrict__ bsum, int* __restrict__ boff)
{
    __shared__ int buf[1024];
    int t = threadIdx.x;
    int v0 = (t < NBLK) ? bsum[t] : 0;
    buf[t] = v0;
    __syncthreads();
    for (int off = 1; off < 1024; off <<= 1) {
        int v = (t >= off) ? buf[t - off] : 0;
        __syncthreads();
        buf[t] += v;
        __syncthreads();
    }
    if (t < NBLK) boff[t] = buf[t] - v0;      // exclusive
}

// ---------------- CSR build: finalize rowptr + cursor ----------------
__global__ __launch_bounds__(256) void scan3_kernel(
    const int* __restrict__ part, const int* __restrict__ boff,
    int* __restrict__ rowptr, int* __restrict__ cursor)
{
    int i = blockIdx.x * 256 + threadIdx.x;
    if (i < NB) {
        int v = part[i] + boff[i >> 8];
        rowptr[i] = v;
        cursor[i] = v;
    }
    if (i == 0) rowptr[NB] = NTOT;
}

// ---------------- CSR build: scatter (edges + self-loops) ----------------
__global__ __launch_bounds__(256) void scatter_kernel(
    const int* __restrict__ ei, int* __restrict__ cursor, int* __restrict__ csr)
{
    int idx = blockIdx.x * 256 + threadIdx.x;
    if (idx >= NTOT) return;
    int bin, src;
    if (idx < R_REL * E_EDGES) {
        int r = idx / E_EDGES, e = idx - r * E_EDGES;
        src = ei[(size_t)r * 2 * E_EDGES + e];
        bin = r * N_NODES + ei[(size_t)r * 2 * E_EDGES + E_EDGES + e];
    } else {
        bin = idx - R_REL * E_EDGES;
        src = bin % N_NODES;
    }
    int pos = atomicAdd(&cursor[bin], 1);
    csr[pos] = src;
}

// ---------------- prep: fp32 -> bf16 pairwise ----------------
__global__ __launch_bounds__(256) void cvt_bf16_kernel(
    const float* __restrict__ src, unsigned* __restrict__ dst, int npairs)
{
    int i = blockIdx.x * 256 + threadIdx.x;
    if (i >= npairs) return;
    float2 v = *(const float2*)(src + 2 * i);
    dst[i] = f2bfbits(v.x) | (f2bfbits(v.y) << 16);
}

// ---------------- prep: W[r][k][256] (l|r) -> Bt[r][512][K] bf16, bias cat ----
__global__ __launch_bounds__(256) void prep_w_kernel(
    const float* __restrict__ Wl, const float* __restrict__ Wr,
    const float* __restrict__ bl, const float* __restrict__ br,
    unsigned short* __restrict__ Bt, float* __restrict__ bcat, int K)
{
    int idx = blockIdx.x * 256 + threadIdx.x;
    if (idx >= R_REL * 512 * K) return;
    int k = idx % K;
    int rn = idx / K;
    int n = rn % 512;
    int r = rn / 512;
    int nn = n & 255;
    const float* W = (n < 256) ? Wl : Wr;
    float w = W[((size_t)r * K + k) * 256 + nn];
    Bt[idx] = (unsigned short)f2bfbits(w);
    if (k == 0)
        bcat[rn] = (n < 256) ? bl[r * 256 + nn] : br[r * 256 + nn];
}

// ---------------- prep: sum GAT biases over relations ----------------
__global__ __launch_bounds__(128) void bias_sum_kernel(
    const float* __restrict__ b1, const float* __restrict__ b2,
    float* __restrict__ o1, float* __restrict__ o2)
{
    int c = threadIdx.x;
    float s1 = 0.f, s2 = 0.f;
    for (int r = 0; r < R_REL; r++) { s1 += b1[r * 128 + c]; s2 += b2[r * 128 + c]; }
    o1[c] = s1; o2[c] = s2;
}

// ---------------- MFMA GEMM: one (m,n,z) tile per block, K-chunked LDS --------
// (round-12 verified kernel, unchanged)
template <int K>
__global__ __launch_bounds__(256, 4) void gemm_mfma_kernel(
    const unsigned short* __restrict__ A,
    const unsigned short* __restrict__ BtAll,   // [R][512][K] bf16 (n-major)
    const float* __restrict__ biasAll,          // [R][512]
    unsigned short* __restrict__ CAll)          // [R][40000][512]
{
    constexpr int KC = (K > 64) ? 64 : K;
    constexpr int NCH = K / KC;
    constexpr int CH = KC / 8;
    constexpr int TB = 128 * KC * 2;
    __shared__ char lds[2 * TB];
    char* ldsA = lds;
    char* ldsB = lds + TB;

    int tid = threadIdx.x;
    int lane = tid & 63, wave = tid >> 6;
    int l16 = lane & 15, quad = lane >> 4;
    int wm = (wave >> 1) * 64, wn = (wave & 1) * 64;
    int ny = blockIdx.x & 3, z = blockIdx.x >> 2;
    int m0 = blockIdx.y * 128, n0 = ny * 128;

    auto SW = [](int row) { return (KC == 64) ? (row & 7) : ((row >> 1) & 3); };

    const char* Bt = (const char*)(BtAll + (size_t)z * 512 * K);

    f32x4 acc[4][4];
#pragma unroll
    for (int i = 0; i < 4; i++)
#pragma unroll
        for (int j = 0; j < 4; j++) {
            acc[i][j][0] = 0.f; acc[i][j][1] = 0.f;
            acc[i][j][2] = 0.f; acc[i][j][3] = 0.f;
        }

    for (int nc = 0; nc < NCH; ++nc) {
        if (nc) __syncthreads();
#pragma unroll
        for (int it = 0; it < (128 * CH) / 256; ++it) {
            int s = it * 256 + tid;
            int row = s / CH, sc = s % CH;
            int c = sc ^ SW(row);
            int gr = m0 + row; gr = gr < N_NODES ? gr : N_NODES - 1;
            const char* gpA = (const char*)A + (size_t)gr * (K * 2) + nc * KC * 2 + c * 16;
            __builtin_amdgcn_global_load_lds(
                (const __attribute__((address_space(1))) void*)gpA,
                (__attribute__((address_space(3))) void*)(ldsA + it * 4096 + wave * 1024), 16, 0, 0);
            const char* gpB = Bt + (size_t)(n0 + row) * (K * 2) + nc * KC * 2 + c * 16;
            __builtin_amdgcn_global_load_lds(
                (const __attribute__((address_space(1))) void*)gpB,
                (__attribute__((address_space(3))) void*)(ldsB + it * 4096 + wave * 1024), 16, 0, 0);
        }
        __syncthreads();

#pragma unroll
        for (int kk = 0; kk < KC / 32; ++kk) {
            bf16x8 af[4], bfr[4];
#pragma unroll
            for (int i = 0; i < 4; ++i) {
                int row = wm + i * 16 + l16;
                int slot = (kk * 4 + quad) ^ SW(row);
                af[i] = *(const bf16x8*)(ldsA + row * (KC * 2) + slot * 16);
            }
#pragma unroll
            for (int j = 0; j < 4; ++j) {
                int row = wn + j * 16 + l16;
                int slot = (kk * 4 + quad) ^ SW(row);
                bfr[j] = *(const bf16x8*)(ldsB + row * (KC * 2) + slot * 16);
            }
#pragma unroll
            for (int i = 0; i < 4; i++)
#pragma unroll
                for (int j = 0; j < 4; j++)
                    acc[i][j] = __builtin_amdgcn_mfma_f32_16x16x32_bf16(af[i], bfr[j], acc[i][j], 0, 0, 0);
        }
    }

    const float* bias = biasAll + z * 512;
    unsigned short* C = CAll + (size_t)z * N_NODES * 512;
    float biasj[4];
#pragma unroll
    for (int j = 0; j < 4; ++j) biasj[j] = bias[n0 + wn + j * 16 + l16];
#pragma unroll
    for (int i = 0; i < 4; i++) {
        int gr0 = m0 + wm + i * 16 + quad * 4;
#pragma unroll
        for (int j = 0; j < 4; j++) {
            int col = n0 + wn + j * 16 + l16;
#pragma unroll
            for (int rg = 0; rg < 4; rg++) {
                float a = acc[i][j][rg] + biasj[j];
                float b = __shfl_xor(a, 1);
                int grow = gr0 + rg;
                if (!(lane & 1) && grow < N_NODES) {
                    __hip_bfloat162 h2 = __float22bfloat162_rn(make_float2(a, b));
                    unsigned u;
                    __builtin_memcpy(&u, &h2, 4);
                    *(unsigned*)((char*)C + ((size_t)grow * 512 + col) * 2) = u;
                }
            }
        }
    }
}

// ------- fused 6-relation GATv2 + sum + tanh + LN; 8ch/lane layout ------------
// XLR row (1024 B): xl head0 ch0-127 [0:256)B, xl head1 [256:512)B, xr [512:1024)B.
// Lane layout: eh = lane>>5 (edge slot A/B), hl = lane&31; lane covers 8 channels
// of head hl>>4 at byte offset hl*16. One wave per dst processes 2 edges/iter;
// logit reduction = 4 shuffles shared by both edges. Per-relation epilogue only
// merges s (1 shuffle); acc-half/head merges + Σbias deferred to once per dst.
__global__ __launch_bounds__(256) void gat6_ln_kernel(
    const unsigned short* __restrict__ XLR,
    const int* __restrict__ rowptr,     // [R*N+1], self-loops included
    const int* __restrict__ csr,        // [NTOT] src indices
    const float* __restrict__ att,      // [R][2][128]
    const float* __restrict__ biasSum,  // [128] = sum_r bias[r]
    const float* __restrict__ lng, const float* __restrict__ lnb,
    unsigned* __restrict__ hout)        // [N][64] packed bf16 pairs (natural ch order)
{
    int lane = threadIdx.x & 63;
    int wv = __builtin_amdgcn_readfirstlane(threadIdx.x) >> 6;   // uniform wave id
    int d = blockIdx.x * 4 + wv;                                  // uniform dst
    int eh = lane >> 5;
    int hl = lane & 31;
    int cs = hl & 15;

    float tot0 = 0.f, tot1 = 0.f, tot2 = 0.f, tot3 = 0.f;
    float tot4 = 0.f, tot5 = 0.f, tot6 = 0.f, tot7 = 0.f;

#pragma unroll 1
    for (int r = 0; r < R_REL; r++) {
        const char* base = (const char*)XLR + (size_t)r * N_NODES * 1024;
        uint4 xru = *(const uint4*)(base + (size_t)d * 1024 + 512 + hl * 16);
        float xr0 = bflo(xru.x), xr1 = bfhi(xru.x), xr2 = bflo(xru.y), xr3 = bfhi(xru.y);
        float xr4 = bflo(xru.z), xr5 = bfhi(xru.z), xr6 = bflo(xru.w), xr7 = bfhi(xru.w);
        float4 a0 = *(const float4*)(att + r * 256 + hl * 8);
        float4 a1 = *(const float4*)(att + r * 256 + hl * 8 + 4);

        int bin = r * N_NODES + d;                 // uniform -> s_load
        int beg = rowptr[bin];
        int end = rowptr[bin + 1];

        float s = 0.f;
        float c0 = 0.f, c1 = 0.f, c2 = 0.f, c3 = 0.f;
        float c4 = 0.f, c5 = 0.f, c6 = 0.f, c7 = 0.f;
        int nit = (end - beg + 1) >> 1;
        int idx = beg + eh;
        for (int t = 0; t < nit; ++t, idx += 2) {
            int valid = idx < end;
            int src = csr[valid ? idx : beg];      // beg always valid (self-loop)
            uint4 u = *(const uint4*)(base + (size_t)src * 1024 + hl * 16);
            float x0 = bflo(u.x), x1 = bfhi(u.x), x2 = bflo(u.y), x3 = bfhi(u.y);
            float x4 = bflo(u.z), x5 = bfhi(u.z), x6 = bflo(u.w), x7 = bfhi(u.w);
            float t0 = x0 + xr0, t1 = x1 + xr1, t2 = x2 + xr2, t3 = x3 + xr3;
            float t4 = x4 + xr4, t5 = x5 + xr5, t6 = x6 + xr6, t7 = x7 + xr7;
            t0 = fmaxf(t0, NEG_SLOPE * t0); t1 = fmaxf(t1, NEG_SLOPE * t1);
            t2 = fmaxf(t2, NEG_SLOPE * t2); t3 = fmaxf(t3, NEG_SLOPE * t3);
            t4 = fmaxf(t4, NEG_SLOPE * t4); t5 = fmaxf(t5, NEG_SLOPE * t5);
            t6 = fmaxf(t6, NEG_SLOPE * t6); t7 = fmaxf(t7, NEG_SLOPE * t7);
            float p = t0 * a0.x;
            p = fmaf(t1, a0.y, p); p = fmaf(t2, a0.z, p); p = fmaf(t3, a0.w, p);
            p = fmaf(t4, a1.x, p); p = fmaf(t5, a1.y, p); p = fmaf(t6, a1.z, p);
            p = fmaf(t7, a1.w, p);
            p += __shfl_xor(p, 8);
            p += __shfl_xor(p, 4);
            p += __shfl_xor(p, 2);
            p += __shfl_xor(p, 1);
            float w = valid ? __expf(fminf(p, 60.f)) : 0.f;
            s += w;
            c0 = fmaf(w, x0, c0); c1 = fmaf(w, x1, c1);
            c2 = fmaf(w, x2, c2); c3 = fmaf(w, x3, c3);
            c4 = fmaf(w, x4, c4); c5 = fmaf(w, x5, c5);
            c6 = fmaf(w, x6, c6); c7 = fmaf(w, x7, c7);
        }
        s += __shfl_xor(s, 32);                   // merge edge halves (per head)
        float rs = 0.5f * __builtin_amdgcn_rcpf(s);   // fold head-mean 0.5
        tot0 = fmaf(c0, rs, tot0); tot1 = fmaf(c1, rs, tot1);
        tot2 = fmaf(c2, rs, tot2); tot3 = fmaf(c3, rs, tot3);
        tot4 = fmaf(c4, rs, tot4); tot5 = fmaf(c5, rs, tot5);
        tot6 = fmaf(c6, rs, tot6); tot7 = fmaf(c7, rs, tot7);
    }
    // merge edge halves (xor32), then heads (xor16) — once per dst
    tot0 += __shfl_xor(tot0, 32); tot1 += __shfl_xor(tot1, 32);
    tot2 += __shfl_xor(tot2, 32); tot3 += __shfl_xor(tot3, 32);
    tot4 += __shfl_xor(tot4, 32); tot5 += __shfl_xor(tot5, 32);
    tot6 += __shfl_xor(tot6, 32); tot7 += __shfl_xor(tot7, 32);
    tot0 += __shfl_xor(tot0, 16); tot1 += __shfl_xor(tot1, 16);
    tot2 += __shfl_xor(tot2, 16); tot3 += __shfl_xor(tot3, 16);
    tot4 += __shfl_xor(tot4, 16); tot5 += __shfl_xor(tot5, 16);
    tot6 += __shfl_xor(tot6, 16); tot7 += __shfl_xor(tot7, 16);
    float4 bs0 = *(const float4*)(biasSum + cs * 8);
    float4 bs1 = *(const float4*)(biasSum + cs * 8 + 4);
    float v0 = tanhf(tot0 + bs0.x), v1 = tanhf(tot1 + bs0.y);
    float v2 = tanhf(tot2 + bs0.z), v3 = tanhf(tot3 + bs0.w);
    float v4 = tanhf(tot4 + bs1.x), v5 = tanhf(tot5 + bs1.y);
    float v6 = tanhf(tot6 + bs1.z), v7 = tanhf(tot7 + bs1.w);
    float sum = v0 + v1 + v2 + v3 + v4 + v5 + v6 + v7;
    float sq = v0 * v0 + v1 * v1 + v2 * v2 + v3 * v3
             + v4 * v4 + v5 * v5 + v6 * v6 + v7 * v7;
#pragma unroll
    for (int off = 8; off >= 1; off >>= 1) {
        sum += __shfl_xor(sum, off);
        sq  += __shfl_xor(sq, off);
    }
    float mean = sum * (1.f / 128.f);
    float var = sq * (1.f / 128.f) - mean * mean;
    float rstd = rsqrtf(var + 1e-5f);
    float4 g0 = *(const float4*)(lng + cs * 8);
    float4 g1 = *(const float4*)(lng + cs * 8 + 4);
    float4 b0 = *(const float4*)(lnb + cs * 8);
    float4 b1 = *(const float4*)(lnb + cs * 8 + 4);
    float o0 = (v0 - mean) * rstd * g0.x + b0.x;
    float o1 = (v1 - mean) * rstd * g0.y + b0.y;
    float o2 = (v2 - mean) * rstd * g0.z + b0.z;
    float o3 = (v3 - mean) * rstd * g0.w + b0.w;
    float o4 = (v4 - mean) * rstd * g1.x + b1.x;
    float o5 = (v5 - mean) * rstd * g1.y + b1.y;
    float o6 = (v6 - mean) * rstd * g1.z + b1.z;
    float o7 = (v7 - mean) * rstd * g1.w + b1.w;
    if (lane < 16) {
        uint4 q;
        q.x = f2bfbits(o0) | (f2bfbits(o1) << 16);
        q.y = f2bfbits(o2) | (f2bfbits(o3) << 16);
        q.z = f2bfbits(o4) | (f2bfbits(o5) << 16);
        q.w = f2bfbits(o6) | (f2bfbits(o7) << 16);
        *((uint4*)((char*)hout + (size_t)d * 256) + cs) = q;
    }
}

// ---------------- attention pooling over bf16 h: one wave per graph -----------
__global__ __launch_bounds__(256) void pool_kernel(
    const unsigned* __restrict__ hb, const float* __restrict__ query,
    float* __restrict__ gout)
{
    int gtid = blockIdx.x * 256 + threadIdx.x;
    int bg = gtid >> 6;
    int lane = threadIdx.x & 63;
    if (bg >= B_GRAPHS) return;
    float2 q = *(const float2*)(query + 2 * lane);
    float mx = -1e30f, ssum = 0.f, g0 = 0.f, g1 = 0.f;
    for (int i = 0; i < NODES_PER_G; i++) {
        unsigned u = hb[(size_t)(bg * NODES_PER_G + i) * 64 + lane];
        float h0 = bflo(u), h1 = bfhi(u);
        float p = h0 * q.x + h1 * q.y;
#pragma unroll
        for (int off = 32; off >= 1; off >>= 1) p += __shfl_xor(p, off, 64);
        float mn = fmaxf(mx, p);
        float sc = __expf(mx - mn), w = __expf(p - mn);
        ssum = ssum * sc + w;
        g0 = g0 * sc + w * h0;
        g1 = g1 * sc + w * h1;
        mx = mn;
    }
    float2 o; o.x = g0 / ssum; o.y = g1 / ssum;
    *(float2*)(gout + (size_t)bg * 128 + 2 * lane) = o;
}

// ---------------- final projection ----------------
__global__ __launch_bounds__(128) void proj_kernel(
    const float* __restrict__ g, const float* __restrict__ W,
    const float* __restrict__ bias, float* __restrict__ out)
{
    int bg = blockIdx.x;
    int o = threadIdx.x;
    const float* gp = g + (size_t)bg * 128;
    float acc = bias[o];
    for (int k = 0; k < 128; k++) acc = fmaf(gp[k], W[k * 128 + o], acc);
    out[(size_t)bg * 128 + o] = acc;
}

extern "C" void kernel_launch(void* const* d_in, const int* in_sizes, int n_in,
                              void* d_out, int out_size, void* d_ws, size_t ws_size,
                              hipStream_t stream)
{
    const float* x     = (const float*)d_in[0];
    const int*   ei    = (const int*)d_in[1];
    const float* Wl1   = (const float*)d_in[3];
    const float* bl1   = (const float*)d_in[4];
    const float* Wr1   = (const float*)d_in[5];
    const float* br1   = (const float*)d_in[6];
    const float* att1  = (const float*)d_in[7];
    const float* bias1 = (const float*)d_in[8];
    const float* Wl2   = (const float*)d_in[9];
    const float* bl2   = (const float*)d_in[10];
    const float* Wr2   = (const float*)d_in[11];
    const float* br2   = (const float*)d_in[12];
    const float* att2  = (const float*)d_in[13];
    const float* bias2 = (const float*)d_in[14];
    const float* ln1g  = (const float*)d_in[15];
    const float* ln1b  = (const float*)d_in[16];
    const float* ln2g  = (const float*)d_in[17];
    const float* ln2b  = (const float*)d_in[18];
    const float* query = (const float*)d_in[19];
    const float* projW = (const float*)d_in[20];
    const float* projb = (const float*)d_in[21];
    float* out = (float*)d_out;

    // workspace layout — all regions rewritten every call
    unsigned short* xlr6 = (unsigned short*)d_ws;                 // 245.76 MB
    unsigned short* h1bf = xlr6 + (size_t)R_REL * N_NODES * 512;  // 10.24 MB
    unsigned short* xbf  = h1bf + (size_t)N_NODES * 128;          // 2.56 MB
    unsigned short* Bt1  = xbf + (size_t)N_NODES * 32;
    unsigned short* Bt2  = Bt1 + R_REL * 512 * 32;
    float* bc1  = (float*)(Bt2 + R_REL * 512 * 128);
    float* bc2  = bc1 + R_REL * 512;
    float* gb   = bc2 + R_REL * 512;                              // 2000*128 f32
    float* bsum1 = gb + (size_t)B_GRAPHS * 128;                   // 128 f32
    float* bsum2 = bsum1 + 128;                                   // 128 f32
    int* cnt    = (int*)(bsum2 + 128);                            // NB
    int* part   = cnt + NB;                                       // NB
    int* rowptr = part + NB;                                      // NB+1
    int* cursor = rowptr + NB + 1;                                // NB
    int* bsum   = cursor + NB;                                    // NBLK
    int* boff   = bsum + NBLK;                                    // NBLK
    int* csr    = boff + NBLK;                                    // NTOT

    // ---- CSR build (self-loops included) ----
    hipMemsetAsync(cnt, 0, sizeof(int) * NB, stream);
    count_kernel<<<(NTOT + 255) / 256, 256, 0, stream>>>(ei, cnt);
    scan1_kernel<<<NBLK, 256, 0, stream>>>(cnt, part, bsum);
    scan2_kernel<<<1, 1024, 0, stream>>>(bsum, boff);
    scan3_kernel<<<NBLK, 256, 0, stream>>>(part, boff, rowptr, cursor);
    scatter_kernel<<<(NTOT + 255) / 256, 256, 0, stream>>>(ei, cursor, csr);

    // ---- prep ----
    cvt_bf16_kernel<<<(N_NODES * 16 + 255) / 256, 256, 0, stream>>>(x, (unsigned*)xbf, N_NODES * 16);
    prep_w_kernel<<<(R_REL * 512 * 32 + 255) / 256, 256, 0, stream>>>(Wl1, Wr1, bl1, br1, Bt1, bc1, 32);
    prep_w_kernel<<<(R_REL * 512 * 128 + 255) / 256, 256, 0, stream>>>(Wl2, Wr2, bl2, br2, Bt2, bc2, 128);
    bias_sum_kernel<<<1, 128, 0, stream>>>(bias1, bias2, bsum1, bsum2);

    dim3 ggrid(24, (N_NODES + 127) / 128, 1);   // x = z*4+ny (same-m adjacent), y = m-tile
    // ---- layer 1 ----
    gemm_mfma_kernel<32><<<ggrid, 256, 0, stream>>>(xbf, Bt1, bc1, xlr6);
    gat6_ln_kernel<<<N_NODES / 4, 256, 0, stream>>>(
        xlr6, rowptr, csr, att1, bsum1, ln1g, ln1b, (unsigned*)h1bf);
    // ---- layer 2 ----
    gemm_mfma_kernel<128><<<ggrid, 256, 0, stream>>>(h1bf, Bt2, bc2, xlr6);
    gat6_ln_kernel<<<N_NODES / 4, 256, 0, stream>>>(
        xlr6, rowptr, csr, att2, bsum2, ln2g, ln2b, (unsigned*)h1bf);
    // ---- pooling + projection ----
    pool_kernel<<<B_GRAPHS / 4, 256, 0, stream>>>((unsigned*)h1bf, query, gb);
    proj_kernel<<<B_GRAPHS, 128, 0, stream>>>(gb, projW, projb, out);
}

// Round 14
// 436.308 us; speedup vs baseline: 1.1077x; 1.1077x over previous
//
#include <hip/hip_runtime.h>
#include <hip/hip_bf16.h>
#include <math.h>

#define N_NODES 40000
#define E_EDGES 60000
#define R_REL 6
#define IN_F 32
#define HID_F 128
#define B_GRAPHS 2000
#define NODES_PER_G 20
#define NEG_SLOPE 0.2f
#define NB (R_REL * N_NODES)            // 240000 bins
#define NTOT (R_REL * (E_EDGES + N_NODES))  // 600000 entries incl. self-loops
#define NBLK ((NB + 255) / 256)         // 938 scan blocks

// fused-prep block ranges
#define CNT_B ((NTOT + 255) / 256)          // 2344
#define CVT_B ((N_NODES * 16 + 255) / 256)  // 2500
#define P1_B  (R_REL * 512 * 32 / 256)      // 384
#define P2_B  (R_REL * 512 * 128 / 256)     // 1536
#define PREP_TOTAL (CNT_B + CVT_B + P1_B + P2_B + 1)

typedef __bf16 bf16x8 __attribute__((ext_vector_type(8)));
typedef float f32x4 __attribute__((ext_vector_type(4)));

__device__ __forceinline__ unsigned f2bfbits(float f) {
    unsigned u = __builtin_bit_cast(unsigned, f);
    return (u + 0x7FFFu + ((u >> 16) & 1u)) >> 16;   // RNE
}
__device__ __forceinline__ float bflo(unsigned u) { return __builtin_bit_cast(float, u << 16); }
__device__ __forceinline__ float bfhi(unsigned u) { return __builtin_bit_cast(float, u & 0xFFFF0000u); }

__device__ __forceinline__ void prep_w_body(
    const float* __restrict__ Wl, const float* __restrict__ Wr,
    const float* __restrict__ bl, const float* __restrict__ br,
    unsigned short* __restrict__ Bt, float* __restrict__ bcat, int K, int idx)
{
    if (idx >= R_REL * 512 * K) return;
    int k = idx % K;
    int rn = idx / K;
    int n = rn % 512;
    int r = rn / 512;
    int nn = n & 255;
    const float* W = (n < 256) ? Wl : Wr;
    float w = W[((size_t)r * K + k) * 256 + nn];
    Bt[idx] = (unsigned short)f2bfbits(w);
    if (k == 0)
        bcat[rn] = (n < 256) ? bl[r * 256 + nn] : br[r * 256 + nn];
}

// ---------------- fused prep: count + cvt + prep_w x2 + bias_sum --------------
__global__ __launch_bounds__(256) void fused_prep_kernel(
    const int* __restrict__ ei, int* __restrict__ cnt,
    const float* __restrict__ x, unsigned* __restrict__ xbf,
    const float* __restrict__ Wl1, const float* __restrict__ Wr1,
    const float* __restrict__ bl1, const float* __restrict__ br1,
    unsigned short* __restrict__ Bt1, float* __restrict__ bc1,
    const float* __restrict__ Wl2, const float* __restrict__ Wr2,
    const float* __restrict__ bl2, const float* __restrict__ br2,
    unsigned short* __restrict__ Bt2, float* __restrict__ bc2,
    const float* __restrict__ bias1, const float* __restrict__ bias2,
    float* __restrict__ bsum1, float* __restrict__ bsum2)
{
    int b = blockIdx.x;
    int tid = threadIdx.x;
    if (b < CNT_B) {
        int idx = b * 256 + tid;
        if (idx >= NTOT) return;
        int bin;
        if (idx < R_REL * E_EDGES) {
            int r = idx / E_EDGES, e = idx - r * E_EDGES;
            bin = r * N_NODES + ei[(size_t)r * 2 * E_EDGES + E_EDGES + e];
        } else {
            bin = idx - R_REL * E_EDGES;   // self-loop
        }
        atomicAdd(&cnt[bin], 1);
    } else if (b < CNT_B + CVT_B) {
        int i = (b - CNT_B) * 256 + tid;
        if (i >= N_NODES * 16) return;
        float2 v = *(const float2*)(x + 2 * i);
        xbf[i] = f2bfbits(v.x) | (f2bfbits(v.y) << 16);
    } else if (b < CNT_B + CVT_B + P1_B) {
        prep_w_body(Wl1, Wr1, bl1, br1, Bt1, bc1, 32, (b - CNT_B - CVT_B) * 256 + tid);
    } else if (b < CNT_B + CVT_B + P1_B + P2_B) {
        prep_w_body(Wl2, Wr2, bl2, br2, Bt2, bc2, 128, (b - CNT_B - CVT_B - P1_B) * 256 + tid);
    } else {
        if (tid >= 128) return;
        float s1 = 0.f, s2 = 0.f;
        for (int r = 0; r < R_REL; r++) { s1 += bias1[r * 128 + tid]; s2 += bias2[r * 128 + tid]; }
        bsum1[tid] = s1; bsum2[tid] = s2;   // bsum kept for layout compat (unused by r12 gat)
    }
}

// ---------------- CSR build: scan level 1 (per-256 block) ----------------
__global__ __launch_bounds__(256) void scan1_kernel(
    const int* __restrict__ cnt, int* __restrict__ part, int* __restrict__ bsum)
{
    int i = blockIdx.x * 256 + threadIdx.x;
    int v = (i < NB) ? cnt[i] : 0;
    int lane = threadIdx.x & 63, w = threadIdx.x >> 6;
    int x = v;
#pragma unroll
    for (int off = 1; off < 64; off <<= 1) {
        int y = __shfl_up(x, off, 64);
        if (lane >= off) x += y;
    }
    __shared__ int ws[4];
    if (lane == 63) ws[w] = x;
    __syncthreads();
    int add = 0;
    for (int j = 0; j < w; j++) add += ws[j];
    int incl = x + add;
    if (i < NB) part[i] = incl - v;           // exclusive within block
    if (threadIdx.x == 255) bsum[blockIdx.x] = incl;
}

// ---------------- CSR build: scan level 2 (938 elems, 256 thr, 1 barrier) -----
__global__ __launch_bounds__(256) void scan2_kernel(
    const int* __restrict__ bsum, int* __restrict__ boff)
{
    __shared__ int ws[4];
    int t = threadIdx.x;
    int lane = t & 63, w = t >> 6;
    int base4 = t * 4;
    int pre[4];
    int s = 0;
#pragma unroll
    for (int j = 0; j < 4; j++) {
        int i = base4 + j;
        int x = (i < NBLK) ? bsum[i] : 0;
        pre[j] = s;
        s += x;
    }
    int incl = s;
#pragma unroll
    for (int off = 1; off < 64; off <<= 1) {
        int y = __shfl_up(incl, off, 64);
        if (lane >= off) incl += y;
    }
    if (lane == 63) ws[w] = incl;
    __syncthreads();
    int wbase = 0;
    for (int j = 0; j < w; j++) wbase += ws[j];
    int tbase = wbase + incl - s;
#pragma unroll
    for (int j = 0; j < 4; j++) {
        int i = base4 + j;
        if (i < NBLK) boff[i] = tbase + pre[j];
    }
}

// ---------------- CSR build: finalize rowptr + cursor ----------------
__global__ __launch_bounds__(256) void scan3_kernel(
    const int* __restrict__ part, const int* __restrict__ boff,
    int* __restrict__ rowptr, int* __restrict__ cursor)
{
    int i = blockIdx.x * 256 + threadIdx.x;
    if (i < NB) {
        int v = part[i] + boff[i >> 8];
        rowptr[i] = v;
        cursor[i] = v;
    }
    if (i == 0) rowptr[NB] = NTOT;
}

// ---------------- CSR build: scatter (edges + self-loops) ----------------
__global__ __launch_bounds__(256) void scatter_kernel(
    const int* __restrict__ ei, int* __restrict__ cursor, int* __restrict__ csr)
{
    int idx = blockIdx.x * 256 + threadIdx.x;
    if (idx >= NTOT) return;
    int bin, src;
    if (idx < R_REL * E_EDGES) {
        int r = idx / E_EDGES, e = idx - r * E_EDGES;
        src = ei[(size_t)r * 2 * E_EDGES + e];
        bin = r * N_NODES + ei[(size_t)r * 2 * E_EDGES + E_EDGES + e];
    } else {
        bin = idx - R_REL * E_EDGES;
        src = bin % N_NODES;
    }
    int pos = atomicAdd(&cursor[bin], 1);
    csr[pos] = src;
}

// ---------------- MFMA GEMM: one (m,n,z) tile per block, K-chunked LDS --------
// (round-12 verified kernel, unchanged)
template <int K>
__global__ __launch_bounds__(256, 4) void gemm_mfma_kernel(
    const unsigned short* __restrict__ A,
    const unsigned short* __restrict__ BtAll,   // [R][512][K] bf16 (n-major)
    const float* __restrict__ biasAll,          // [R][512]
    unsigned short* __restrict__ CAll)          // [R][40000][512]
{
    constexpr int KC = (K > 64) ? 64 : K;
    constexpr int NCH = K / KC;
    constexpr int CH = KC / 8;
    constexpr int TB = 128 * KC * 2;
    __shared__ char lds[2 * TB];
    char* ldsA = lds;
    char* ldsB = lds + TB;

    int tid = threadIdx.x;
    int lane = tid & 63, wave = tid >> 6;
    int l16 = lane & 15, quad = lane >> 4;
    int wm = (wave >> 1) * 64, wn = (wave & 1) * 64;
    int ny = blockIdx.x & 3, z = blockIdx.x >> 2;
    int m0 = blockIdx.y * 128, n0 = ny * 128;

    auto SW = [](int row) { return (KC == 64) ? (row & 7) : ((row >> 1) & 3); };

    const char* Bt = (const char*)(BtAll + (size_t)z * 512 * K);

    f32x4 acc[4][4];
#pragma unroll
    for (int i = 0; i < 4; i++)
#pragma unroll
        for (int j = 0; j < 4; j++) {
            acc[i][j][0] = 0.f; acc[i][j][1] = 0.f;
            acc[i][j][2] = 0.f; acc[i][j][3] = 0.f;
        }

    for (int nc = 0; nc < NCH; ++nc) {
        if (nc) __syncthreads();
#pragma unroll
        for (int it = 0; it < (128 * CH) / 256; ++it) {
            int s = it * 256 + tid;
            int row = s / CH, sc = s % CH;
            int c = sc ^ SW(row);
            int gr = m0 + row; gr = gr < N_NODES ? gr : N_NODES - 1;
            const char* gpA = (const char*)A + (size_t)gr * (K * 2) + nc * KC * 2 + c * 16;
            __builtin_amdgcn_global_load_lds(
                (const __attribute__((address_space(1))) void*)gpA,
                (__attribute__((address_space(3))) void*)(ldsA + it * 4096 + wave * 1024), 16, 0, 0);
            const char* gpB = Bt + (size_t)(n0 + row) * (K * 2) + nc * KC * 2 + c * 16;
            __builtin_amdgcn_global_load_lds(
                (const __attribute__((address_space(1))) void*)gpB,
                (__attribute__((address_space(3))) void*)(ldsB + it * 4096 + wave * 1024), 16, 0, 0);
        }
        __syncthreads();

#pragma unroll
        for (int kk = 0; kk < KC / 32; ++kk) {
            bf16x8 af[4], bfr[4];
#pragma unroll
            for (int i = 0; i < 4; ++i) {
                int row = wm + i * 16 + l16;
                int slot = (kk * 4 + quad) ^ SW(row);
                af[i] = *(const bf16x8*)(ldsA + row * (KC * 2) + slot * 16);
            }
#pragma unroll
            for (int j = 0; j < 4; ++j) {
                int row = wn + j * 16 + l16;
                int slot = (kk * 4 + quad) ^ SW(row);
                bfr[j] = *(const bf16x8*)(ldsB + row * (KC * 2) + slot * 16);
            }
#pragma unroll
            for (int i = 0; i < 4; i++)
#pragma unroll
                for (int j = 0; j < 4; j++)
                    acc[i][j] = __builtin_amdgcn_mfma_f32_16x16x32_bf16(af[i], bfr[j], acc[i][j], 0, 0, 0);
        }
    }

    const float* bias = biasAll + z * 512;
    unsigned short* C = CAll + (size_t)z * N_NODES * 512;
    float biasj[4];
#pragma unroll
    for (int j = 0; j < 4; ++j) biasj[j] = bias[n0 + wn + j * 16 + l16];
#pragma unroll
    for (int i = 0; i < 4; i++) {
        int gr0 = m0 + wm + i * 16 + quad * 4;
#pragma unroll
        for (int j = 0; j < 4; j++) {
            int col = n0 + wn + j * 16 + l16;
#pragma unroll
            for (int rg = 0; rg < 4; rg++) {
                float a = acc[i][j][rg] + biasj[j];
                float b = __shfl_xor(a, 1);
                int grow = gr0 + rg;
                if (!(lane & 1) && grow < N_NODES) {
                    __hip_bfloat162 h2 = __float22bfloat162_rn(make_float2(a, b));
                    unsigned u;
                    __builtin_memcpy(&u, &h2, 4);
                    *(unsigned*)((char*)C + ((size_t)grow * 512 + col) * 2) = u;
                }
            }
        }
    }
}

// ------- fused 6-relation GATv2 + relation-sum + tanh + LayerNorm, CSR --------
// (round-12 verified kernel, unchanged: one wave per dst, per-relation loop,
//  pairwise edges with independent accumulators, no-max softmax)
__global__ __launch_bounds__(256) void gat6_ln_kernel(
    const unsigned short* __restrict__ XLR,
    const int* __restrict__ rowptr,   // [R*N+1], self-loops included
    const int* __restrict__ csr,      // [NTOT] src indices
    const float* __restrict__ att,    // [R][2][128]
    const float* __restrict__ bias,   // [R][128]
    const float* __restrict__ lng, const float* __restrict__ lnb,
    unsigned* __restrict__ hout)      // [N][64] packed bf16 pairs
{
    int gtid = blockIdx.x * 256 + threadIdx.x;
    int d = gtid >> 6;
    int lane = threadIdx.x & 63;
    if (d >= N_NODES) return;
    int hl = lane & 31;

    float tot0 = 0.f, tot1 = 0.f, tot2 = 0.f, tot3 = 0.f;
#pragma unroll 1
    for (int r = 0; r < R_REL; r++) {
        const char* base = (const char*)XLR + (size_t)r * N_NODES * 1024;
        const unsigned* xrp = (const unsigned*)(base + (size_t)d * 1024 + 512 + lane * 8);
        unsigned xu0 = xrp[0], xu1 = xrp[1];
        float xr0 = bflo(xu0), xr1 = bfhi(xu0), xr2 = bflo(xu1), xr3 = bfhi(xu1);
        float4 av = *(const float4*)(att + r * 256 + lane * 4);

        int bin = r * N_NODES + d;
        int beg = __builtin_amdgcn_readfirstlane(rowptr[bin]);
        int end = __builtin_amdgcn_readfirstlane(rowptr[bin + 1]);

        float sA = 0.f, a0 = 0.f, a1 = 0.f, a2 = 0.f, a3 = 0.f;
        float sB = 0.f, b0 = 0.f, b1 = 0.f, b2 = 0.f, b3 = 0.f;
        int i = beg;
        for (; i + 2 <= end; i += 2) {
            int s0 = csr[i], s1 = csr[i + 1];
            const unsigned* pA = (const unsigned*)(base + (size_t)s0 * 1024 + lane * 8);
            const unsigned* pB = (const unsigned*)(base + (size_t)s1 * 1024 + lane * 8);
            unsigned uA0 = pA[0], uA1 = pA[1];
            unsigned uB0 = pB[0], uB1 = pB[1];
            float xA0 = bflo(uA0), xA1 = bfhi(uA0), xA2 = bflo(uA1), xA3 = bfhi(uA1);
            float xB0 = bflo(uB0), xB1 = bfhi(uB0), xB2 = bflo(uB1), xB3 = bfhi(uB1);
            float tA0 = xA0 + xr0, tA1 = xA1 + xr1, tA2 = xA2 + xr2, tA3 = xA3 + xr3;
            float tB0 = xB0 + xr0, tB1 = xB1 + xr1, tB2 = xB2 + xr2, tB3 = xB3 + xr3;
            tA0 = fmaxf(tA0, NEG_SLOPE * tA0); tB0 = fmaxf(tB0, NEG_SLOPE * tB0);
            tA1 = fmaxf(tA1, NEG_SLOPE * tA1); tB1 = fmaxf(tB1, NEG_SLOPE * tB1);
            tA2 = fmaxf(tA2, NEG_SLOPE * tA2); tB2 = fmaxf(tB2, NEG_SLOPE * tB2);
            tA3 = fmaxf(tA3, NEG_SLOPE * tA3); tB3 = fmaxf(tB3, NEG_SLOPE * tB3);
            float pa = tA0 * av.x + tA1 * av.y + tA2 * av.z + tA3 * av.w;
            float pb = tB0 * av.x + tB1 * av.y + tB2 * av.z + tB3 * av.w;
            pa += __shfl_xor(pa, 16); pb += __shfl_xor(pb, 16);
            pa += __shfl_xor(pa, 8);  pb += __shfl_xor(pb, 8);
            pa += __shfl_xor(pa, 4);  pb += __shfl_xor(pb, 4);
            pa += __shfl_xor(pa, 2);  pb += __shfl_xor(pb, 2);
            pa += __shfl_xor(pa, 1);  pb += __shfl_xor(pb, 1);
            float wa = __expf(fminf(pa, 60.f));
            float wb = __expf(fminf(pb, 60.f));
            sA += wa; sB += wb;
            a0 = fmaf(wa, xA0, a0); b0 = fmaf(wb, xB0, b0);
            a1 = fmaf(wa, xA1, a1); b1 = fmaf(wb, xB1, b1);
            a2 = fmaf(wa, xA2, a2); b2 = fmaf(wb, xB2, b2);
            a3 = fmaf(wa, xA3, a3); b3 = fmaf(wb, xB3, b3);
        }
        if (i < end) {
            int s0 = csr[i];
            const unsigned* pA = (const unsigned*)(base + (size_t)s0 * 1024 + lane * 8);
            unsigned uA0 = pA[0], uA1 = pA[1];
            float xA0 = bflo(uA0), xA1 = bfhi(uA0), xA2 = bflo(uA1), xA3 = bfhi(uA1);
            float tA0 = xA0 + xr0, tA1 = xA1 + xr1, tA2 = xA2 + xr2, tA3 = xA3 + xr3;
            tA0 = fmaxf(tA0, NEG_SLOPE * tA0);
            tA1 = fmaxf(tA1, NEG_SLOPE * tA1);
            tA2 = fmaxf(tA2, NEG_SLOPE * tA2);
            tA3 = fmaxf(tA3, NEG_SLOPE * tA3);
            float pa = tA0 * av.x + tA1 * av.y + tA2 * av.z + tA3 * av.w;
            pa += __shfl_xor(pa, 16);
            pa += __shfl_xor(pa, 8);
            pa += __shfl_xor(pa, 4);
            pa += __shfl_xor(pa, 2);
            pa += __shfl_xor(pa, 1);
            float wa = __expf(fminf(pa, 60.f));
            sA += wa;
            a0 = fmaf(wa, xA0, a0);
            a1 = fmaf(wa, xA1, a1);
            a2 = fmaf(wa, xA2, a2);
            a3 = fmaf(wa, xA3, a3);
        }
        sA += sB; a0 += b0; a1 += b1; a2 += b2; a3 += b3;
        float rs = 0.5f * __builtin_amdgcn_rcpf(sA);   // fold head-mean 0.5
        float o0 = a0 * rs, o1 = a1 * rs, o2 = a2 * rs, o3 = a3 * rs;
        o0 += __shfl_xor(o0, 32);
        o1 += __shfl_xor(o1, 32);
        o2 += __shfl_xor(o2, 32);
        o3 += __shfl_xor(o3, 32);
        float4 bv = *(const float4*)(bias + r * 128 + hl * 4);
        tot0 += o0 + bv.x;
        tot1 += o1 + bv.y;
        tot2 += o2 + bv.z;
        tot3 += o3 + bv.w;
    }
    // tanh + layernorm (128 ch replicated in each 32-lane half)
    float v0 = tanhf(tot0), v1 = tanhf(tot1), v2 = tanhf(tot2), v3 = tanhf(tot3);
    float sum = v0 + v1 + v2 + v3;
    float sq = v0 * v0 + v1 * v1 + v2 * v2 + v3 * v3;
#pragma unroll
    for (int off = 16; off >= 1; off >>= 1) {
        sum += __shfl_xor(sum, off);
        sq  += __shfl_xor(sq, off);
    }
    float mean = sum * (1.f / 128.f);
    float var = sq * (1.f / 128.f) - mean * mean;
    float rstd = rsqrtf(var + 1e-5f);
    float4 gg = *(const float4*)(lng + hl * 4);
    float4 bb = *(const float4*)(lnb + hl * 4);
    float o0 = (v0 - mean) * rstd * gg.x + bb.x;
    float o1 = (v1 - mean) * rstd * gg.y + bb.y;
    float o2 = (v2 - mean) * rstd * gg.z + bb.z;
    float o3 = (v3 - mean) * rstd * gg.w + bb.w;
    if (lane < 32) {
        uint2 q;
        q.x = f2bfbits(o0) | (f2bfbits(o1) << 16);
        q.y = f2bfbits(o2) | (f2bfbits(o3) << 16);
        *((uint2*)(hout + (size_t)d * 64) + hl) = q;
    }
}

// ---------------- fused attention pooling + projection ----------------
// 4 waves/block = 4 graphs; pooled g stays in LDS; projection matvec in-block.
__global__ __launch_bounds__(256) void pool_proj_kernel(
    const unsigned* __restrict__ hb, const float* __restrict__ query,
    const float* __restrict__ W, const float* __restrict__ pb,
    float* __restrict__ out)
{
    __shared__ float gL[4][128];
    int wave = threadIdx.x >> 6;
    int lane = threadIdx.x & 63;
    int bg = blockIdx.x * 4 + wave;          // grid exact: bg < 2000 always
    float2 q = *(const float2*)(query + 2 * lane);
    float mx = -1e30f, ssum = 0.f, g0 = 0.f, g1 = 0.f;
    for (int i = 0; i < NODES_PER_G; i++) {
        unsigned u = hb[(size_t)(bg * NODES_PER_G + i) * 64 + lane];
        float h0 = bflo(u), h1 = bfhi(u);
        float p = h0 * q.x + h1 * q.y;
#pragma unroll
        for (int off = 32; off >= 1; off >>= 1) p += __shfl_xor(p, off, 64);
        float mn = fmaxf(mx, p);
        float sc = __expf(mx - mn), w = __expf(p - mn);
        ssum = ssum * sc + w;
        g0 = g0 * sc + w * h0;
        g1 = g1 * sc + w * h1;
        mx = mn;
    }
    float inv = 1.f / ssum;
    gL[wave][2 * lane] = g0 * inv;
    gL[wave][2 * lane + 1] = g1 * inv;
    __syncthreads();
    int o0 = lane, o1 = lane + 64;
    float a0 = pb[o0], a1 = pb[o1];
    for (int k = 0; k < 128; k++) {
        float gk = gL[wave][k];
        a0 = fmaf(gk, W[k * 128 + o0], a0);
        a1 = fmaf(gk, W[k * 128 + o1], a1);
    }
    out[(size_t)bg * 128 + o0] = a0;
    out[(size_t)bg * 128 + o1] = a1;
}

extern "C" void kernel_launch(void* const* d_in, const int* in_sizes, int n_in,
                              void* d_out, int out_size, void* d_ws, size_t ws_size,
                              hipStream_t stream)
{
    const float* x     = (const float*)d_in[0];
    const int*   ei    = (const int*)d_in[1];
    const float* Wl1   = (const float*)d_in[3];
    const float* bl1   = (const float*)d_in[4];
    const float* Wr1   = (const float*)d_in[5];
    const float* br1   = (const float*)d_in[6];
    const float* att1  = (const float*)d_in[7];
    const float* bias1 = (const float*)d_in[8];
    const float* Wl2   = (const float*)d_in[9];
    const float* bl2   = (const float*)d_in[10];
    const float* Wr2   = (const float*)d_in[11];
    const float* br2   = (const float*)d_in[12];
    const float* att2  = (const float*)d_in[13];
    const float* bias2 = (const float*)d_in[14];
    const float* ln1g  = (const float*)d_in[15];
    const float* ln1b  = (const float*)d_in[16];
    const float* ln2g  = (const float*)d_in[17];
    const float* ln2b  = (const float*)d_in[18];
    const float* query = (const float*)d_in[19];
    const float* projW = (const float*)d_in[20];
    const float* projb = (const float*)d_in[21];
    float* out = (float*)d_out;

    // workspace layout — all regions rewritten every call
    unsigned short* xlr6 = (unsigned short*)d_ws;                 // 245.76 MB
    unsigned short* h1bf = xlr6 + (size_t)R_REL * N_NODES * 512;  // 10.24 MB
    unsigned short* xbf  = h1bf + (size_t)N_NODES * 128;          // 2.56 MB
    unsigned short* Bt1  = xbf + (size_t)N_NODES * 32;
    unsigned short* Bt2  = Bt1 + R_REL * 512 * 32;
    float* bc1  = (float*)(Bt2 + R_REL * 512 * 128);
    float* bc2  = bc1 + R_REL * 512;
    float* bsum1 = bc2 + R_REL * 512;                             // 128 f32
    float* bsum2 = bsum1 + 128;                                   // 128 f32
    int* cnt    = (int*)(bsum2 + 128);                            // NB
    int* part   = cnt + NB;                                       // NB
    int* rowptr = part + NB;                                      // NB+1
    int* cursor = rowptr + NB + 1;                                // NB
    int* bsum   = cursor + NB;                                    // NBLK
    int* boff   = bsum + NBLK;                                    // NBLK
    int* csr    = boff + NBLK;                                    // NTOT

    // ---- CSR build + prep (fused) ----
    hipMemsetAsync(cnt, 0, sizeof(int) * NB, stream);
    fused_prep_kernel<<<PREP_TOTAL, 256, 0, stream>>>(
        ei, cnt, x, (unsigned*)xbf,
        Wl1, Wr1, bl1, br1, Bt1, bc1,
        Wl2, Wr2, bl2, br2, Bt2, bc2,
        bias1, bias2, bsum1, bsum2);
    scan1_kernel<<<NBLK, 256, 0, stream>>>(cnt, part, bsum);
    scan2_kernel<<<1, 256, 0, stream>>>(bsum, boff);
    scan3_kernel<<<NBLK, 256, 0, stream>>>(part, boff, rowptr, cursor);
    scatter_kernel<<<(NTOT + 255) / 256, 256, 0, stream>>>(ei, cursor, csr);

    dim3 ggrid(24, (N_NODES + 127) / 128, 1);   // x = z*4+ny (same-m adjacent), y = m-tile
    // ---- layer 1 ----
    gemm_mfma_kernel<32><<<ggrid, 256, 0, stream>>>(xbf, Bt1, bc1, xlr6);
    gat6_ln_kernel<<<N_NODES / 4, 256, 0, stream>>>(
        xlr6, rowptr, csr, att1, bias1, ln1g, ln1b, (unsigned*)h1bf);
    // ---- layer 2 ----
    gemm_mfma_kernel<128><<<ggrid, 256, 0, stream>>>(h1bf, Bt2, bc2, xlr6);
    gat6_ln_kernel<<<N_NODES / 4, 256, 0, stream>>>(
        xlr6, rowptr, csr, att2, bias2, ln2g, ln2b, (unsigned*)h1bf);
    // ---- pooling + projection (fused) ----
    pool_proj_kernel<<<B_GRAPHS / 4, 256, 0, stream>>>(
        (unsigned*)h1bf, query, projW, projb, out);
}